// Round 10
// baseline (793.577 us; speedup 1.0000x reference)
//
#include <hip/hip_runtime.h>
#include <math.h>

#define N_NODES 100000
#define NREL 3
#define E_PER 1600000
#define E_TOT 4800000
#define EP 500000
#define F_IN 128
#define F_HID 64
#define F_OUT 16
#define NRN 300000   // NREL*N_NODES

// two-level histogram params (R2-proven; random global atomics measured
// ~26G/s in R3 -> LDS-privatized + sequential flush is mandatory)
// R18: dynamic LDS 80 KB/block (2 blocks/CU = 160 KB, occupancy unchanged)
#define NSEG 5
#define SEGSZ 20000          // 5*20000 = 100000 exactly; ed passes 14 -> 10
#define NBLK 32
#define CHUNK (E_PER / NBLK) // 50000 edges/block (div by 4)
// packed-16-bit histout: counts per block-chunk <= 50000 < 2^16
#define SEGO 40000           // bins/segment, packed 2/word -> 80 KB dynamic LDS
#define NSEGO 3              // ceil(100000/40000); es re-read 3x not 4x

// ---------------- CSR-path ws layout (element offsets) ----------------
#define OFF_DOUT    0           // 300000: int counts -> float rsqrt in place
#define OFF_DINVIN  300000      // 300000 f
#define OFF_CNT     600000      // 300000 i: in-deg counts
#define OFF_G       900000      // 300000 i: CSR offsets (exclusive prefix)
#define OFF_BSUM    1200000     // 1024 i
#define OFF_CSR     1201024     // 4800000 i: dst-sorted src indices
#define OFF_ESLOT   6001024     // 4800000 i  (alias w/ hproj region)
#define OFF_HPROJ   6001024     // 6400064 f ((N+1) rows x 64) / 2x hp2 bufs
#define OFF_H1      12401088    // 6400000 f
#define OFF_HP22    18801088    // 3200032 f ((N+1) rows x 32)
#define WS_NEED_CSR 22001120    // 88.005 MB
#define HP2SZ 3200032           // (N_NODES+1)*32
// ---------------- fallback (R7 atomic-scatter) layout ----------------
#define ODINV_OUT 0
#define ODINV_IN  300000
#define OH1ACC    600000
#define OHPROJ    7000000
#define OL2ACC    13400000

__device__ __forceinline__ float atomAddF(float* p, float v) {
    return unsafeAtomicAdd(p, v);
}

__device__ __forceinline__ unsigned rotl32(unsigned x, unsigned d) {
    return (x << d) | (x >> (32u - d));
}

// jax.random.normal(key(42), (100000,16)) — partitionable threefry2x32,
// counter (0,i), key (0,42), XOR-folded output words. Verified PASS R7-R18.
__device__ float jax_noise(unsigned i) {
    const unsigned ks0 = 0u, ks1 = 42u;
    const unsigned ks2 = ks0 ^ ks1 ^ 0x1BD11BDAu;
    unsigned x0 = 0u + ks0;
    unsigned x1 = i + ks1;
#define TFR(r) { x0 += x1; x1 = rotl32(x1, r); x1 ^= x0; }
    TFR(13) TFR(15) TFR(26) TFR(6)
    x0 += ks1; x1 += ks2 + 1u;
    TFR(17) TFR(29) TFR(16) TFR(24)
    x0 += ks2; x1 += ks0 + 2u;
    TFR(13) TFR(15) TFR(26) TFR(6)
    x0 += ks0; x1 += ks1 + 3u;
    TFR(17) TFR(29) TFR(16) TFR(24)
    x0 += ks1; x1 += ks2 + 4u;
    TFR(13) TFR(15) TFR(26) TFR(6)
    x0 += ks2; x1 += ks0 + 5u;
#undef TFR
    const unsigned bits = x0 ^ x1;
    float f = __uint_as_float((bits >> 9) | 0x3f800000u) - 1.0f;
    const float lo = -0.99999994f;
    float u = fmaxf(lo, f * 2.0f + lo);
    float w = -log1pf(-u * u);
    float p;
    if (w < 5.0f) {
        w -= 2.5f;
        p = 2.81022636e-08f;
        p = fmaf(p, w, 3.43273939e-07f);
        p = fmaf(p, w, -3.5233877e-06f);
        p = fmaf(p, w, -4.39150654e-06f);
        p = fmaf(p, w, 0.00021858087f);
        p = fmaf(p, w, -0.00125372503f);
        p = fmaf(p, w, -0.00417768164f);
        p = fmaf(p, w, 0.246640727f);
        p = fmaf(p, w, 1.50140941f);
    } else {
        w = sqrtf(w) - 3.0f;
        p = -0.000200214257f;
        p = fmaf(p, w, 0.000100950558f);
        p = fmaf(p, w, 0.00134934322f);
        p = fmaf(p, w, -0.00367342844f);
        p = fmaf(p, w, 0.00573950773f);
        p = fmaf(p, w, -0.0076224613f);
        p = fmaf(p, w, 0.00943887047f);
        p = fmaf(p, w, 1.00167406f);
        p = fmaf(p, w, 2.83297682f);
    }
    return 1.41421356237f * (p * u);
}

// ------------------------------------------------------ two-level histograms
// in-degree counts + per-edge CSR slot; dynamic 80 KB LDS, 5 segments.
__global__ __launch_bounds__(512) void k_histin(const int* __restrict__ ed,
                                                int* __restrict__ cnt,
                                                int* __restrict__ eslot) {
    extern __shared__ int lds[];
    const int r = blockIdx.z, g = blockIdx.y, b = blockIdx.x;
    const int lo = g * SEGSZ;
    const int hi = min(lo + SEGSZ, N_NODES);
    const int nbins = hi - lo;
    for (int i = threadIdx.x; i < nbins; i += 512) lds[i] = 0;
    __syncthreads();
    const int e0 = r * E_PER + b * CHUNK;
    const int e1 = e0 + CHUNK;
    // phase 1: private count, 4 edges/thread/iter
    for (int e = e0 + threadIdx.x * 4; e + 4 <= e1; e += 512 * 4) {
        const int4 d4 = *(const int4*)(ed + e);
        if (d4.x >= lo && d4.x < hi) atomicAdd(&lds[d4.x - lo], 1);
        if (d4.y >= lo && d4.y < hi) atomicAdd(&lds[d4.y - lo], 1);
        if (d4.z >= lo && d4.z < hi) atomicAdd(&lds[d4.z - lo], 1);
        if (d4.w >= lo && d4.w < hi) atomicAdd(&lds[d4.w - lo], 1);
    }
    __syncthreads();
    // phase 2: flush; fetch-add return = this block's exclusive base per bin
    // (sequential-address atomics: consecutive threads -> consecutive bins)
    for (int i = threadIdx.x; i < nbins; i += 512) {
        const int c = lds[i];
        lds[i] = c ? atomicAdd(&cnt[r * N_NODES + lo + i], c) : 0;
    }
    __syncthreads();
    // phase 3: final slot = LDS fetch-add from base
    for (int e = e0 + threadIdx.x * 4; e + 4 <= e1; e += 512 * 4) {
        const int4 d4 = *(const int4*)(ed + e);
        if (d4.x >= lo && d4.x < hi) eslot[e]     = atomicAdd(&lds[d4.x - lo], 1);
        if (d4.y >= lo && d4.y < hi) eslot[e + 1] = atomicAdd(&lds[d4.y - lo], 1);
        if (d4.z >= lo && d4.z < hi) eslot[e + 2] = atomicAdd(&lds[d4.z - lo], 1);
        if (d4.w >= lo && d4.w < hi) eslot[e + 3] = atomicAdd(&lds[d4.w - lo], 1);
    }
}

// out-degree counts, 16-bit packed (2 bins/word); dynamic 80 KB, 3 segments.
__global__ __launch_bounds__(512) void k_histout(const int* __restrict__ es,
                                                 int* __restrict__ dout) {
    extern __shared__ int lds[];
    const int r = blockIdx.z, g = blockIdx.y, b = blockIdx.x;
    const int lo = g * SEGO;
    const int hi = min(lo + SEGO, N_NODES);
    const int nbins = hi - lo;
    const int nwords = (nbins + 1) >> 1;
    for (int i = threadIdx.x; i < nwords; i += 512) lds[i] = 0;
    __syncthreads();
    const int e0 = r * E_PER + b * CHUNK;
    const int e1 = e0 + CHUNK;
    for (int e = e0 + threadIdx.x * 4; e + 4 <= e1; e += 512 * 4) {
        const int4 s4 = *(const int4*)(es + e);
        if (s4.x >= lo && s4.x < hi) {
            const int i = s4.x - lo;
            atomicAdd(&lds[i >> 1], 1 << ((i & 1) * 16));
        }
        if (s4.y >= lo && s4.y < hi) {
            const int i = s4.y - lo;
            atomicAdd(&lds[i >> 1], 1 << ((i & 1) * 16));
        }
        if (s4.z >= lo && s4.z < hi) {
            const int i = s4.z - lo;
            atomicAdd(&lds[i >> 1], 1 << ((i & 1) * 16));
        }
        if (s4.w >= lo && s4.w < hi) {
            const int i = s4.w - lo;
            atomicAdd(&lds[i >> 1], 1 << ((i & 1) * 16));
        }
    }
    __syncthreads();
    for (int i = threadIdx.x; i < nwords; i += 512) {
        const unsigned c = (unsigned)lds[i];
        const int c0 = (int)(c & 0xffffu);
        const int c1 = (int)(c >> 16);
        if (c0) atomicAdd(&dout[r * N_NODES + lo + 2 * i], c0);
        if (c1 && 2 * i + 1 < nbins)
            atomicAdd(&dout[r * N_NODES + lo + 2 * i + 1], c1);
    }
}

__global__ __launch_bounds__(256) void k_scanA(const int* __restrict__ cnt,
                                               int* __restrict__ bsum) {
    __shared__ int red[256];
    const int base = blockIdx.x * 1024 + threadIdx.x * 4;
    int s = 0;
#pragma unroll
    for (int q = 0; q < 4; ++q) {
        const int i = base + q;
        s += (i < NRN) ? cnt[i] : 0;
    }
    red[threadIdx.x] = s;
    __syncthreads();
    for (int w = 128; w > 0; w >>= 1) {
        if (threadIdx.x < w) red[threadIdx.x] += red[threadIdx.x + w];
        __syncthreads();
    }
    if (threadIdx.x == 0) bsum[blockIdx.x] = red[0];
}

__global__ __launch_bounds__(512) void k_scanB(int* __restrict__ bsum) {
    __shared__ int sc[512];
    const int t = threadIdx.x;
    sc[t] = (t < 294) ? bsum[t] : 0;
    __syncthreads();
    for (int o = 1; o < 512; o <<= 1) {
        const int v = (t >= o) ? sc[t - o] : 0;
        __syncthreads();
        sc[t] += v;
        __syncthreads();
    }
    bsum[t] = (t > 0) ? sc[t - 1] : 0;
}

__global__ __launch_bounds__(256) void k_scanC(const int* __restrict__ cnt,
                                               const int* __restrict__ bsum,
                                               int* __restrict__ G,
                                               float* __restrict__ dinv_in,
                                               int* doutc) {
    __shared__ int sc[256];
    const int t = threadIdx.x;
    const int base = blockIdx.x * 1024 + t * 4;
    int v[4];
    int ts = 0;
#pragma unroll
    for (int q = 0; q < 4; ++q) {
        const int i = base + q;
        v[q] = (i < NRN) ? cnt[i] : 0;
        ts += v[q];
    }
    sc[t] = ts;
    __syncthreads();
    for (int o = 1; o < 256; o <<= 1) {
        const int x = (t >= o) ? sc[t - o] : 0;
        __syncthreads();
        sc[t] += x;
        __syncthreads();
    }
    int run = bsum[blockIdx.x] + ((t > 0) ? sc[t - 1] : 0);
#pragma unroll
    for (int q = 0; q < 4; ++q) {
        const int i = base + q;
        if (i < NRN) {
            G[i] = run;
            dinv_in[i] = rsqrtf((float)max(v[q], 1));
            const int oc = doutc[i];
            ((float*)doutc)[i] = rsqrtf((float)max(oc, 1));
        }
        run += v[q];
    }
}

// atomic-free CSR fill, 4 edges/thread via int4.
__global__ __launch_bounds__(256) void k_fill(const int* __restrict__ es,
                                              const int* __restrict__ ed,
                                              const int* __restrict__ eslot,
                                              const int* __restrict__ G,
                                              int* __restrict__ csr) {
    const int r = blockIdx.y;
    const int e = (blockIdx.x * 256 + threadIdx.x) * 4;
    if (e + 4 > E_PER) return;
    const int gid = r * E_PER + e;
    const int4 s4 = *(const int4*)(es + gid);
    const int4 d4 = *(const int4*)(ed + gid);
    const int4 l4 = *(const int4*)(eslot + gid);
    const int rb = r * N_NODES;
    csr[G[rb + d4.x] + l4.x] = s4.x;
    csr[G[rb + d4.y] + l4.y] = s4.y;
    csr[G[rb + d4.z] + l4.z] = s4.z;
    csr[G[rb + d4.w] + l4.w] = s4.w;
}

// R20: gather1 reverted from R19's ballot-sweep (FAILED: absmax 3388 ~=
// NSEGG=13x duplication -> cross-lane ballot/shfl selection inside a
// divergent while-loop is not trustworthy on gfx950) and restructured to
// the PROVEN gather2_all pattern: 4 nodes/wave (16 lanes/node = full
// 64-feat row via float4), direct csr broadcast reads (no 64-wide tile
// staging: csr traffic 25.6 -> 6.4 MB/dispatch), 4 edges in flight,
// zero cross-lane ops. Tail edges read the zeroed pad row (index N_NODES).
__global__ __launch_bounds__(256) void k_gather1(const float* __restrict__ hp,
                                                 const int* __restrict__ csr,
                                                 const int* __restrict__ G,
                                                 const float* __restrict__ dinv,
                                                 float* __restrict__ h1,
                                                 int rbase, int first) {
    const int node = (blockIdx.x * 256 + threadIdx.x) >> 4;   // 16 lanes/node
    const int l16 = threadIdx.x & 15;
    const int idx = rbase + node;
    const int off0 = G[idx];
    const int off1 = (idx == NRN - 1) ? E_TOT : G[idx + 1];
    const int deg = off1 - off0;
    float ax = 0.f, ay = 0.f, az = 0.f, aw = 0.f;
    for (int e0 = 0; e0 < deg; e0 += 4) {
        const int sA = csr[off0 + e0];
        const int sB = (e0 + 1 < deg) ? csr[off0 + e0 + 1] : N_NODES;
        const int sC = (e0 + 2 < deg) ? csr[off0 + e0 + 2] : N_NODES;
        const int sD = (e0 + 3 < deg) ? csr[off0 + e0 + 3] : N_NODES;
        const float4 vA = *(const float4*)(hp + (size_t)sA * F_HID + l16 * 4);
        const float4 vB = *(const float4*)(hp + (size_t)sB * F_HID + l16 * 4);
        const float4 vC = *(const float4*)(hp + (size_t)sC * F_HID + l16 * 4);
        const float4 vD = *(const float4*)(hp + (size_t)sD * F_HID + l16 * 4);
        ax += vA.x; ay += vA.y; az += vA.z; aw += vA.w;
        ax += vB.x; ay += vB.y; az += vB.z; aw += vB.w;
        ax += vC.x; ay += vC.y; az += vC.z; aw += vC.w;
        ax += vD.x; ay += vD.y; az += vD.z; aw += vD.w;
    }
    const float dv = dinv[idx];
    float4* dst = (float4*)(h1 + (size_t)node * F_HID) + l16;
    float4 o;
    if (first) {
        o.x = dv * ax; o.y = dv * ay; o.z = dv * az; o.w = dv * aw;
    } else {
        const float4 pr = *dst;
        o.x = pr.x + dv * ax; o.y = pr.y + dv * ay;
        o.z = pr.z + dv * az; o.w = pr.w + dv * aw;
    }
    *dst = o;
}

// R18: 4 nodes/wave, 8 edges in flight per node. (Unchanged; proven.)
__global__ __launch_bounds__(256) void k_gather2_all(const float* __restrict__ hp0,
                                                     const float* __restrict__ hp1,
                                                     const float* __restrict__ hp2,
                                                     const int* __restrict__ csr,
                                                     const int* __restrict__ G,
                                                     const float* __restrict__ dinv,
                                                     const float* __restrict__ bmu,
                                                     const float* __restrict__ bls,
                                                     float* __restrict__ outh) {
    const int node = (blockIdx.x * 256 + threadIdx.x) >> 4;   // 16 lanes/node
    const int lane = threadIdx.x & 63;
    const int gl = lane & 15;        // group-local lane (feature id in epilogue)
    const int l8 = lane & 7;         // slice id (4 floats per slice)
    const int e2 = (lane >> 3) & 1;  // which of 2 base edges
    float ox = 0.f, oy = 0.f, oz = 0.f, ow = 0.f;
#pragma unroll
    for (int r = 0; r < NREL; ++r) {
        const float* hp = (r == 0) ? hp0 : (r == 1) ? hp1 : hp2;
        const int idx = r * N_NODES + node;
        const int off0 = G[idx];
        const int off1 = (idx == NRN - 1) ? E_TOT : G[idx + 1];
        const int deg = off1 - off0;
        float ax = 0.f, ay = 0.f, az = 0.f, aw = 0.f;
        for (int ei0 = 0; ei0 < deg; ei0 += 8) {
            const int eiA = ei0 + e2;
            const int eiB = ei0 + 2 + e2;
            const int eiC = ei0 + 4 + e2;
            const int eiD = ei0 + 6 + e2;
            const int sA = (eiA < deg) ? csr[off0 + eiA] : N_NODES;  // pad row=0
            const int sB = (eiB < deg) ? csr[off0 + eiB] : N_NODES;
            const int sC = (eiC < deg) ? csr[off0 + eiC] : N_NODES;
            const int sD = (eiD < deg) ? csr[off0 + eiD] : N_NODES;
            const float4 vA = *(const float4*)(hp + (size_t)sA * 32 + l8 * 4);
            const float4 vB = *(const float4*)(hp + (size_t)sB * 32 + l8 * 4);
            const float4 vC = *(const float4*)(hp + (size_t)sC * 32 + l8 * 4);
            const float4 vD = *(const float4*)(hp + (size_t)sD * 32 + l8 * 4);
            ax += vA.x; ay += vA.y; az += vA.z; aw += vA.w;
            ax += vB.x; ay += vB.y; az += vB.z; aw += vB.w;
            ax += vC.x; ay += vC.y; az += vC.z; aw += vC.w;
            ax += vD.x; ay += vD.y; az += vD.z; aw += vD.w;
        }
        // combine the two 8-lane edge groups within this node's 16 lanes
        ax += __shfl_xor(ax, 8);
        ay += __shfl_xor(ay, 8);
        az += __shfl_xor(az, 8);
        aw += __shfl_xor(aw, 8);
        const float dv = dinv[idx];
        ox = fmaf(dv, ax, ox);
        oy = fmaf(dv, ay, oy);
        oz = fmaf(dv, az, oz);
        ow = fmaf(dv, aw, ow);
    }
    // redistribution within each 16-lane group: lane gl owns feature gl.
    const int gb = lane & 48;                 // group base lane
    const int srcM = gb + (gl >> 2);
    const int srcL = gb + 4 + (gl >> 2);
    const float m0 = __shfl(ox, srcM), m1 = __shfl(oy, srcM),
                m2 = __shfl(oz, srcM), m3 = __shfl(ow, srcM);
    const float s0 = __shfl(ox, srcL), s1 = __shfl(oy, srcL),
                s2 = __shfl(oz, srcL), s3 = __shfl(ow, srcL);
    const float mm = (gl & 2) ? ((gl & 1) ? m3 : m2) : ((gl & 1) ? m1 : m0);
    const float ss = (gl & 2) ? ((gl & 1) ? s3 : s2) : ((gl & 1) ? s1 : s0);
    const float mean = mm + bmu[gl] + bmu[16 + gl] + bmu[32 + gl];
    const float lstd = ss + bls[gl] + bls[16 + gl] + bls[32 + gl];
    outh[(size_t)node * 16 + gl] =
        mean + jax_noise((unsigned)(node * 16 + gl)) * expf(lstd);
}

// ------------------------------------------------------ projections
// 4 output channels per thread -> 4 independent FMA chains, float4 loads.
__global__ __launch_bounds__(256) void k_project1(const float* __restrict__ x,
                                                  const float* __restrict__ W,
                                                  const float* __restrict__ dinv,
                                                  float* __restrict__ out) {
    __shared__ float ws[F_IN * F_HID];
    for (int i = threadIdx.x; i < F_IN * F_HID; i += 256) ws[i] = W[i];
    __syncthreads();
    for (int t = blockIdx.x * 256 + threadIdx.x; t < (N_NODES + 1) * 16;
         t += gridDim.x * 256) {
        const int n = t >> 4;
        const int c0 = (t & 15) << 2;
        const int nn = min(n, N_NODES - 1);
        const float4* xr = (const float4*)(x + (size_t)nn * F_IN);
        float a0 = 0.f, a1 = 0.f, a2 = 0.f, a3 = 0.f;
#pragma unroll 8
        for (int k4 = 0; k4 < F_IN / 4; ++k4) {
            const float4 xv = xr[k4];
            const float4 w0 = *(const float4*)(ws + (k4 * 4 + 0) * F_HID + c0);
            const float4 w1 = *(const float4*)(ws + (k4 * 4 + 1) * F_HID + c0);
            const float4 w2 = *(const float4*)(ws + (k4 * 4 + 2) * F_HID + c0);
            const float4 w3 = *(const float4*)(ws + (k4 * 4 + 3) * F_HID + c0);
            a0 = fmaf(xv.x, w0.x, a0); a1 = fmaf(xv.x, w0.y, a1);
            a2 = fmaf(xv.x, w0.z, a2); a3 = fmaf(xv.x, w0.w, a3);
            a0 = fmaf(xv.y, w1.x, a0); a1 = fmaf(xv.y, w1.y, a1);
            a2 = fmaf(xv.y, w1.z, a2); a3 = fmaf(xv.y, w1.w, a3);
            a0 = fmaf(xv.z, w2.x, a0); a1 = fmaf(xv.z, w2.y, a1);
            a2 = fmaf(xv.z, w2.z, a2); a3 = fmaf(xv.z, w2.w, a3);
            a0 = fmaf(xv.w, w3.x, a0); a1 = fmaf(xv.w, w3.y, a1);
            a2 = fmaf(xv.w, w3.z, a2); a3 = fmaf(xv.w, w3.w, a3);
        }
        const float dv = (n < N_NODES) ? dinv[nn] : 0.f;
        float4 o;
        o.x = a0 * dv; o.y = a1 * dv; o.z = a2 * dv; o.w = a3 * dv;
        *(float4*)(out + (size_t)n * F_HID + c0) = o;
    }
}

// R18: all 3 relations in one pass — h1 read once (was 3x), relu once,
// 3 weight sets in 24 KB LDS, writes hp20/hp21/hp22. Same k-order -> exact.
__global__ __launch_bounds__(256) void k_project2_all(const float* __restrict__ h1,
                                                      const float* __restrict__ b0,
                                                      const float* __restrict__ Wmu,
                                                      const float* __restrict__ Wls,
                                                      const float* __restrict__ dinv,
                                                      float* __restrict__ o0,
                                                      float* __restrict__ o1,
                                                      float* __restrict__ o2) {
    __shared__ float ws[NREL * F_HID * 32];
    __shared__ float bs[F_HID];
    for (int i = threadIdx.x; i < NREL * F_HID * 32; i += 256) {
        const int r = i >> 11;          // /2048
        const int j = i & 2047;
        const int k = j >> 5, c = j & 31;
        ws[i] = (c < 16) ? Wmu[r * F_HID * 16 + k * 16 + c]
                         : Wls[r * F_HID * 16 + k * 16 + (c - 16)];
    }
    if (threadIdx.x < F_HID)
        bs[threadIdx.x] = b0[threadIdx.x] + b0[64 + threadIdx.x] + b0[128 + threadIdx.x];
    __syncthreads();
    for (int t = blockIdx.x * 256 + threadIdx.x; t < (N_NODES + 1) * 8;
         t += gridDim.x * 256) {
        const int n = t >> 3;
        const int c0 = (t & 7) << 2;
        const int nn = min(n, N_NODES - 1);
        const float4* hr = (const float4*)(h1 + (size_t)nn * F_HID);
        float a00 = 0.f, a01 = 0.f, a02 = 0.f, a03 = 0.f;
        float a10 = 0.f, a11 = 0.f, a12 = 0.f, a13 = 0.f;
        float a20 = 0.f, a21 = 0.f, a22 = 0.f, a23 = 0.f;
#pragma unroll 2
        for (int k4 = 0; k4 < F_HID / 4; ++k4) {
            const float4 hv = hr[k4];
            const float4 bv = *(const float4*)(bs + k4 * 4);
            const float r0 = fmaxf(hv.x + bv.x, 0.f);
            const float r1 = fmaxf(hv.y + bv.y, 0.f);
            const float r2 = fmaxf(hv.z + bv.z, 0.f);
            const float r3 = fmaxf(hv.w + bv.w, 0.f);
#pragma unroll
            for (int rr = 0; rr < NREL; ++rr) {
                const float* wb = ws + rr * F_HID * 32;
                const float4 w0 = *(const float4*)(wb + (k4 * 4 + 0) * 32 + c0);
                const float4 w1 = *(const float4*)(wb + (k4 * 4 + 1) * 32 + c0);
                const float4 w2 = *(const float4*)(wb + (k4 * 4 + 2) * 32 + c0);
                const float4 w3 = *(const float4*)(wb + (k4 * 4 + 3) * 32 + c0);
                float* pa0 = (rr == 0) ? &a00 : (rr == 1) ? &a10 : &a20;
                float* pa1 = (rr == 0) ? &a01 : (rr == 1) ? &a11 : &a21;
                float* pa2 = (rr == 0) ? &a02 : (rr == 1) ? &a12 : &a22;
                float* pa3 = (rr == 0) ? &a03 : (rr == 1) ? &a13 : &a23;
                *pa0 = fmaf(r0, w0.x, *pa0); *pa1 = fmaf(r0, w0.y, *pa1);
                *pa2 = fmaf(r0, w0.z, *pa2); *pa3 = fmaf(r0, w0.w, *pa3);
                *pa0 = fmaf(r1, w1.x, *pa0); *pa1 = fmaf(r1, w1.y, *pa1);
                *pa2 = fmaf(r1, w1.z, *pa2); *pa3 = fmaf(r1, w1.w, *pa3);
                *pa0 = fmaf(r2, w2.x, *pa0); *pa1 = fmaf(r2, w2.y, *pa1);
                *pa2 = fmaf(r2, w2.z, *pa2); *pa3 = fmaf(r2, w2.w, *pa3);
                *pa0 = fmaf(r3, w3.x, *pa0); *pa1 = fmaf(r3, w3.y, *pa1);
                *pa2 = fmaf(r3, w3.z, *pa2); *pa3 = fmaf(r3, w3.w, *pa3);
            }
        }
        const bool valid = (n < N_NODES);
        const float dv0 = valid ? dinv[nn] : 0.f;
        const float dv1 = valid ? dinv[N_NODES + nn] : 0.f;
        const float dv2 = valid ? dinv[2 * N_NODES + nn] : 0.f;
        float4 q;
        q.x = a00 * dv0; q.y = a01 * dv0; q.z = a02 * dv0; q.w = a03 * dv0;
        *(float4*)(o0 + (size_t)n * 32 + c0) = q;
        q.x = a10 * dv1; q.y = a11 * dv1; q.z = a12 * dv1; q.w = a13 * dv1;
        *(float4*)(o1 + (size_t)n * 32 + c0) = q;
        q.x = a20 * dv2; q.y = a21 * dv2; q.z = a22 * dv2; q.w = a23 * dv2;
        *(float4*)(o2 + (size_t)n * 32 + c0) = q;
    }
}

// kept for the fallback path
__global__ __launch_bounds__(256) void k_project2(const float* __restrict__ h1,
                                                  const float* __restrict__ b0,
                                                  const float* __restrict__ Wmu,
                                                  const float* __restrict__ Wls,
                                                  const float* __restrict__ dinv,
                                                  float* __restrict__ out) {
    __shared__ float ws[F_HID * 32];
    __shared__ float bs[F_HID];
    for (int i = threadIdx.x; i < F_HID * 32; i += 256) {
        const int k = i >> 5, c = i & 31;
        ws[i] = (c < 16) ? Wmu[k * 16 + c] : Wls[k * 16 + (c - 16)];
    }
    if (threadIdx.x < F_HID)
        bs[threadIdx.x] = b0[threadIdx.x] + b0[64 + threadIdx.x] + b0[128 + threadIdx.x];
    __syncthreads();
    for (int t = blockIdx.x * 256 + threadIdx.x; t < (N_NODES + 1) * 8;
         t += gridDim.x * 256) {
        const int n = t >> 3;
        const int c0 = (t & 7) << 2;
        const int nn = min(n, N_NODES - 1);
        const float4* hr = (const float4*)(h1 + (size_t)nn * F_HID);
        float a0 = 0.f, a1 = 0.f, a2 = 0.f, a3 = 0.f;
#pragma unroll 4
        for (int k4 = 0; k4 < F_HID / 4; ++k4) {
            const float4 hv = hr[k4];
            const float4 bv = *(const float4*)(bs + k4 * 4);
            const float r0 = fmaxf(hv.x + bv.x, 0.f);
            const float r1 = fmaxf(hv.y + bv.y, 0.f);
            const float r2 = fmaxf(hv.z + bv.z, 0.f);
            const float r3 = fmaxf(hv.w + bv.w, 0.f);
            const float4 w0 = *(const float4*)(ws + (k4 * 4 + 0) * 32 + c0);
            const float4 w1 = *(const float4*)(ws + (k4 * 4 + 1) * 32 + c0);
            const float4 w2 = *(const float4*)(ws + (k4 * 4 + 2) * 32 + c0);
            const float4 w3 = *(const float4*)(ws + (k4 * 4 + 3) * 32 + c0);
            a0 = fmaf(r0, w0.x, a0); a1 = fmaf(r0, w0.y, a1);
            a2 = fmaf(r0, w0.z, a2); a3 = fmaf(r0, w0.w, a3);
            a0 = fmaf(r1, w1.x, a0); a1 = fmaf(r1, w1.y, a1);
            a2 = fmaf(r1, w1.z, a2); a3 = fmaf(r1, w1.w, a3);
            a0 = fmaf(r2, w2.x, a0); a1 = fmaf(r2, w2.y, a1);
            a2 = fmaf(r2, w2.z, a2); a3 = fmaf(r2, w2.w, a3);
            a0 = fmaf(r3, w3.x, a0); a1 = fmaf(r3, w3.y, a1);
            a2 = fmaf(r3, w3.z, a2); a3 = fmaf(r3, w3.w, a3);
        }
        const float dv = (n < N_NODES) ? dinv[nn] : 0.f;
        float4 o;
        o.x = a0 * dv; o.y = a1 * dv; o.z = a2 * dv; o.w = a3 * dv;
        *(float4*)(out + (size_t)n * 32 + c0) = o;
    }
}

__global__ __launch_bounds__(256) void k_scores(const int* __restrict__ ps,
                                                const int* __restrict__ pd,
                                                const int* __restrict__ ns,
                                                const int* __restrict__ nd,
                                                const float* __restrict__ h,
                                                float* __restrict__ out) {
    const int i = blockIdx.x * 256 + threadIdx.x;
    if (i >= 2 * EP) return;
    const int j = (i < EP) ? i : i - EP;
    const int a = (i < EP) ? ps[j] : ns[j];
    const int b = (i < EP) ? pd[j] : nd[j];
    const float4* ha = (const float4*)(h + (size_t)a * 16);
    const float4* hb = (const float4*)(h + (size_t)b * 16);
    float s = 0.f;
#pragma unroll
    for (int q = 0; q < 4; ++q) {
        const float4 u = ha[q];
        const float4 v = hb[q];
        s += u.x * v.x + u.y * v.y + u.z * v.z + u.w * v.w;
    }
    out[i] = s;
}

// --------------------------------------------- fallback (R7 atomic-scatter)
__global__ __launch_bounds__(256) void k_degrees(const int* __restrict__ es,
                                                 const int* __restrict__ ed,
                                                 float* __restrict__ dout,
                                                 float* __restrict__ din) {
    const int r = blockIdx.y;
    const int e = blockIdx.x * 256 + threadIdx.x;
    const int s = es[r * E_PER + e];
    const int d = ed[r * E_PER + e];
    atomAddF(&dout[r * N_NODES + s], 1.0f);
    atomAddF(&din[r * N_NODES + d], 1.0f);
}

__global__ __launch_bounds__(256) void k_finalize_deg(float* __restrict__ d) {
    const int i = blockIdx.x * 256 + threadIdx.x;
    if (i < 2 * NRN) d[i] = 1.0f / sqrtf(fmaxf(d[i], 1.0f));
}

__global__ __launch_bounds__(256) void k_scatter1(const float* __restrict__ hp,
                                                  const int* __restrict__ es,
                                                  const int* __restrict__ ed,
                                                  const float* __restrict__ din,
                                                  float* __restrict__ acc) {
    const int t = blockIdx.x * 256 + threadIdx.x;
    const int e = t >> 6;
    const int lane = t & 63;
    const int s = es[e];
    const int d = ed[e];
    const float v = hp[s * F_HID + lane] * din[d];
    atomAddF(&acc[d * F_HID + lane], v);
}

__global__ __launch_bounds__(256) void k_scatter2(const float* __restrict__ hp,
                                                  const int* __restrict__ es,
                                                  const int* __restrict__ ed,
                                                  const float* __restrict__ din,
                                                  float* __restrict__ acc) {
    const int t = blockIdx.x * 256 + threadIdx.x;
    const int e = t >> 5;
    const int c = t & 31;
    const int s = es[e];
    const int d = ed[e];
    const float v = hp[s * 32 + c] * din[d];
    atomAddF(&acc[d * 32 + c], v);
}

__global__ __launch_bounds__(256) void k_finalize(const float* __restrict__ l2,
                                                  const float* __restrict__ bmu,
                                                  const float* __restrict__ bls,
                                                  float* __restrict__ outh) {
    const int i = blockIdx.x * 256 + threadIdx.x;
    const int n = i >> 4, c = i & 15;
    const float mean = l2[n * 32 + c] + bmu[c] + bmu[16 + c] + bmu[32 + c];
    const float lstd = l2[n * 32 + 16 + c] + bls[c] + bls[16 + c] + bls[32 + c];
    const float z = jax_noise((unsigned)i);
    outh[i] = mean + z * expf(lstd);
}

extern "C" void kernel_launch(void* const* d_in, const int* in_sizes, int n_in,
                              void* d_out, int out_size, void* d_ws, size_t ws_size,
                              hipStream_t stream) {
    const float* x   = (const float*)d_in[0];
    const float* W0  = (const float*)d_in[1];
    const float* b0  = (const float*)d_in[2];
    const float* Wmu = (const float*)d_in[3];
    const float* bmu = (const float*)d_in[4];
    const float* Wls = (const float*)d_in[5];
    const float* bls = (const float*)d_in[6];
    const int* es = (const int*)d_in[7];
    const int* ed = (const int*)d_in[8];
    const int* ps = (const int*)d_in[9];
    const int* pd = (const int*)d_in[10];
    const int* ns = (const int*)d_in[11];
    const int* nd = (const int*)d_in[12];
    float* out = (float*)d_out;
    float* wsf = (float*)d_ws;

    if (ws_size >= (size_t)WS_NEED_CSR * sizeof(float)) {
        // ---------------- CSR path ----------------
        int*   doutc   = (int*)(wsf + OFF_DOUT);    // int counts -> float rsqrt
        float* doutf   = wsf + OFF_DOUT;            // float view after scanC
        float* dinv_in = wsf + OFF_DINVIN;
        int*   cnt     = (int*)(wsf + OFF_CNT);
        int*   G       = (int*)(wsf + OFF_G);
        int*   bsum    = (int*)(wsf + OFF_BSUM);
        int*   csr     = (int*)(wsf + OFF_CSR);
        int*   eslot   = (int*)(wsf + OFF_ESLOT);   // aliases hproj region
        float* hproj   = wsf + OFF_HPROJ;           // (N+1) x 64, layer 1
        float* hp20    = wsf + OFF_HPROJ;           // (N+1) x 32, layer 2 r0
        float* hp21    = wsf + OFF_HPROJ + HP2SZ;   // (N+1) x 32, layer 2 r1
        float* hp22    = wsf + OFF_HP22;            // (N+1) x 32, layer 2 r2
        float* h1acc   = wsf + OFF_H1;

        hipMemsetAsync(doutc, 0, (size_t)NRN * sizeof(int), stream);
        hipMemsetAsync(cnt, 0, (size_t)NRN * sizeof(int), stream);

        k_histin<<<dim3(NBLK, NSEG, NREL), 512, SEGSZ * sizeof(int), stream>>>(
            ed, cnt, eslot);
        k_histout<<<dim3(NBLK, NSEGO, NREL), 512, (SEGO / 2) * sizeof(int), stream>>>(
            es, doutc);
        k_scanA<<<294, 256, 0, stream>>>(cnt, bsum);
        k_scanB<<<1, 512, 0, stream>>>(bsum);
        k_scanC<<<294, 256, 0, stream>>>(cnt, bsum, G, dinv_in, doutc);
        k_fill<<<dim3((E_PER / 4 + 255) / 256, NREL), 256, 0, stream>>>(
            es, ed, eslot, G, csr);

        for (int r = 0; r < NREL; ++r) {
            k_project1<<<1280, 256, 0, stream>>>(
                x, W0 + (size_t)r * F_IN * F_HID, doutf + (size_t)r * N_NODES, hproj);
            k_gather1<<<N_NODES / 16, 256, 0, stream>>>(
                hproj, csr, G, dinv_in, h1acc, r * N_NODES, r == 0);
        }
        k_project2_all<<<1024, 256, 0, stream>>>(
            h1acc, b0, Wmu, Wls, doutf, hp20, hp21, hp22);
        k_gather2_all<<<N_NODES / 16, 256, 0, stream>>>(
            hp20, hp21, hp22, csr, G, dinv_in, bmu, bls, out + 2 * EP);
        k_scores<<<(2 * EP + 255) / 256, 256, 0, stream>>>(
            ps, pd, ns, nd, out + 2 * EP, out);
    } else {
        // ---------------- fallback: proven R7 atomic path ----------------
        float* dinv_out = wsf + ODINV_OUT;
        float* dinv_in  = wsf + ODINV_IN;
        float* h1acc    = wsf + OH1ACC;
        float* hproj    = wsf + OHPROJ;
        float* l2acc    = wsf + OL2ACC;

        hipMemsetAsync(dinv_out, 0, (size_t)2 * NRN * sizeof(float), stream);
        hipMemsetAsync(h1acc, 0, (size_t)N_NODES * F_HID * sizeof(float), stream);
        hipMemsetAsync(l2acc, 0, (size_t)N_NODES * 32 * sizeof(float), stream);

        k_degrees<<<dim3(E_PER / 256, NREL), 256, 0, stream>>>(es, ed, dinv_out, dinv_in);
        k_finalize_deg<<<(2 * NRN + 255) / 256, 256, 0, stream>>>(wsf);

        for (int r = 0; r < NREL; ++r) {
            k_project1<<<1280, 256, 0, stream>>>(
                x, W0 + (size_t)r * F_IN * F_HID, dinv_out + (size_t)r * N_NODES, hproj);
            k_scatter1<<<E_PER / 4, 256, 0, stream>>>(
                hproj, es + (size_t)r * E_PER, ed + (size_t)r * E_PER,
                dinv_in + (size_t)r * N_NODES, h1acc);
        }
        for (int r = 0; r < NREL; ++r) {
            k_project2<<<1024, 256, 0, stream>>>(
                h1acc, b0, Wmu + (size_t)r * F_HID * F_OUT,
                Wls + (size_t)r * F_HID * F_OUT, dinv_out + (size_t)r * N_NODES, hproj);
            k_scatter2<<<E_PER / 8, 256, 0, stream>>>(
                hproj, es + (size_t)r * E_PER, ed + (size_t)r * E_PER,
                dinv_in + (size_t)r * N_NODES, l2acc);
        }
        k_finalize<<<N_NODES * F_OUT / 256, 256, 0, stream>>>(
            l2acc, bmu, bls, out + 2 * EP);
        k_scores<<<(2 * EP + 255) / 256, 256, 0, stream>>>(
            ps, pd, ns, nd, out + 2 * EP, out);
    }
}

// Round 11
// 791.519 us; speedup vs baseline: 1.0026x; 1.0026x over previous
//
#include <hip/hip_runtime.h>
#include <math.h>

#define N_NODES 100000
#define NREL 3
#define E_PER 1600000
#define E_TOT 4800000
#define EP 500000
#define F_IN 128
#define F_HID 64
#define F_OUT 16
#define NRN 300000   // NREL*N_NODES

// two-level histogram params (R2-proven; random global atomics measured
// ~26G/s in R3 -> LDS-privatized + sequential flush is mandatory)
// R18: dynamic LDS 80 KB/block (2 blocks/CU = 160 KB, occupancy unchanged)
#define NSEG 5
#define SEGSZ 20000          // 5*20000 = 100000 exactly; ed passes 14 -> 10
#define NBLK 32
#define CHUNK (E_PER / NBLK) // 50000 edges/block (div by 4)
// packed-16-bit histout: counts per block-chunk <= 50000 < 2^16
#define SEGO 40000           // bins/segment, packed 2/word -> 80 KB dynamic LDS
#define NSEGO 3              // ceil(100000/40000); es re-read 3x not 4x

// ---------------- CSR-path ws layout (element offsets) ----------------
#define OFF_DOUT    0           // 300000: int counts -> float rsqrt in place
#define OFF_DINVIN  300000      // 300000 f
#define OFF_CNT     600000      // 300000 i: in-deg counts
#define OFF_G       900000      // 300000 i: CSR offsets (exclusive prefix)
#define OFF_BSUM    1200000     // 1024 i
#define OFF_CSR     1201024     // 4800000 i: dst-sorted src indices
#define OFF_ESLOT   6001024     // 4800000 i  (alias w/ hproj region)
#define OFF_HPROJ   6001024     // 6400064 f ((N+1) rows x 64) / 2x hp2 bufs
#define OFF_H1      12401088    // 6400000 f
#define OFF_HP22    18801088    // 3200032 f ((N+1) rows x 32)
#define WS_NEED_CSR 22001120    // 88.005 MB
#define HP2SZ 3200032           // (N_NODES+1)*32
// ---------------- fallback (R7 atomic-scatter) layout ----------------
#define ODINV_OUT 0
#define ODINV_IN  300000
#define OH1ACC    600000
#define OHPROJ    7000000
#define OL2ACC    13400000

__device__ __forceinline__ float atomAddF(float* p, float v) {
    return unsafeAtomicAdd(p, v);
}

__device__ __forceinline__ unsigned rotl32(unsigned x, unsigned d) {
    return (x << d) | (x >> (32u - d));
}

// jax.random.normal(key(42), (100000,16)) — partitionable threefry2x32,
// counter (0,i), key (0,42), XOR-folded output words. Verified PASS R7-R20.
__device__ float jax_noise(unsigned i) {
    const unsigned ks0 = 0u, ks1 = 42u;
    const unsigned ks2 = ks0 ^ ks1 ^ 0x1BD11BDAu;
    unsigned x0 = 0u + ks0;
    unsigned x1 = i + ks1;
#define TFR(r) { x0 += x1; x1 = rotl32(x1, r); x1 ^= x0; }
    TFR(13) TFR(15) TFR(26) TFR(6)
    x0 += ks1; x1 += ks2 + 1u;
    TFR(17) TFR(29) TFR(16) TFR(24)
    x0 += ks2; x1 += ks0 + 2u;
    TFR(13) TFR(15) TFR(26) TFR(6)
    x0 += ks0; x1 += ks1 + 3u;
    TFR(17) TFR(29) TFR(16) TFR(24)
    x0 += ks1; x1 += ks2 + 4u;
    TFR(13) TFR(15) TFR(26) TFR(6)
    x0 += ks2; x1 += ks0 + 5u;
#undef TFR
    const unsigned bits = x0 ^ x1;
    float f = __uint_as_float((bits >> 9) | 0x3f800000u) - 1.0f;
    const float lo = -0.99999994f;
    float u = fmaxf(lo, f * 2.0f + lo);
    float w = -log1pf(-u * u);
    float p;
    if (w < 5.0f) {
        w -= 2.5f;
        p = 2.81022636e-08f;
        p = fmaf(p, w, 3.43273939e-07f);
        p = fmaf(p, w, -3.5233877e-06f);
        p = fmaf(p, w, -4.39150654e-06f);
        p = fmaf(p, w, 0.00021858087f);
        p = fmaf(p, w, -0.00125372503f);
        p = fmaf(p, w, -0.00417768164f);
        p = fmaf(p, w, 0.246640727f);
        p = fmaf(p, w, 1.50140941f);
    } else {
        w = sqrtf(w) - 3.0f;
        p = -0.000200214257f;
        p = fmaf(p, w, 0.000100950558f);
        p = fmaf(p, w, 0.00134934322f);
        p = fmaf(p, w, -0.00367342844f);
        p = fmaf(p, w, 0.00573950773f);
        p = fmaf(p, w, -0.0076224613f);
        p = fmaf(p, w, 0.00943887047f);
        p = fmaf(p, w, 1.00167406f);
        p = fmaf(p, w, 2.83297682f);
    }
    return 1.41421356237f * (p * u);
}

// ------------------------------------------------------ two-level histograms
// in-degree counts + per-edge CSR slot; dynamic 80 KB LDS, 5 segments.
__global__ __launch_bounds__(512) void k_histin(const int* __restrict__ ed,
                                                int* __restrict__ cnt,
                                                int* __restrict__ eslot) {
    extern __shared__ int lds[];
    const int r = blockIdx.z, g = blockIdx.y, b = blockIdx.x;
    const int lo = g * SEGSZ;
    const int hi = min(lo + SEGSZ, N_NODES);
    const int nbins = hi - lo;
    for (int i = threadIdx.x; i < nbins; i += 512) lds[i] = 0;
    __syncthreads();
    const int e0 = r * E_PER + b * CHUNK;
    const int e1 = e0 + CHUNK;
    // phase 1: private count, 4 edges/thread/iter
    for (int e = e0 + threadIdx.x * 4; e + 4 <= e1; e += 512 * 4) {
        const int4 d4 = *(const int4*)(ed + e);
        if (d4.x >= lo && d4.x < hi) atomicAdd(&lds[d4.x - lo], 1);
        if (d4.y >= lo && d4.y < hi) atomicAdd(&lds[d4.y - lo], 1);
        if (d4.z >= lo && d4.z < hi) atomicAdd(&lds[d4.z - lo], 1);
        if (d4.w >= lo && d4.w < hi) atomicAdd(&lds[d4.w - lo], 1);
    }
    __syncthreads();
    // phase 2: flush; fetch-add return = this block's exclusive base per bin
    // (sequential-address atomics: consecutive threads -> consecutive bins)
    for (int i = threadIdx.x; i < nbins; i += 512) {
        const int c = lds[i];
        lds[i] = c ? atomicAdd(&cnt[r * N_NODES + lo + i], c) : 0;
    }
    __syncthreads();
    // phase 3: final slot = LDS fetch-add from base
    for (int e = e0 + threadIdx.x * 4; e + 4 <= e1; e += 512 * 4) {
        const int4 d4 = *(const int4*)(ed + e);
        if (d4.x >= lo && d4.x < hi) eslot[e]     = atomicAdd(&lds[d4.x - lo], 1);
        if (d4.y >= lo && d4.y < hi) eslot[e + 1] = atomicAdd(&lds[d4.y - lo], 1);
        if (d4.z >= lo && d4.z < hi) eslot[e + 2] = atomicAdd(&lds[d4.z - lo], 1);
        if (d4.w >= lo && d4.w < hi) eslot[e + 3] = atomicAdd(&lds[d4.w - lo], 1);
    }
}

// out-degree counts, 16-bit packed (2 bins/word); dynamic 80 KB, 3 segments.
__global__ __launch_bounds__(512) void k_histout(const int* __restrict__ es,
                                                 int* __restrict__ dout) {
    extern __shared__ int lds[];
    const int r = blockIdx.z, g = blockIdx.y, b = blockIdx.x;
    const int lo = g * SEGO;
    const int hi = min(lo + SEGO, N_NODES);
    const int nbins = hi - lo;
    const int nwords = (nbins + 1) >> 1;
    for (int i = threadIdx.x; i < nwords; i += 512) lds[i] = 0;
    __syncthreads();
    const int e0 = r * E_PER + b * CHUNK;
    const int e1 = e0 + CHUNK;
    for (int e = e0 + threadIdx.x * 4; e + 4 <= e1; e += 512 * 4) {
        const int4 s4 = *(const int4*)(es + e);
        if (s4.x >= lo && s4.x < hi) {
            const int i = s4.x - lo;
            atomicAdd(&lds[i >> 1], 1 << ((i & 1) * 16));
        }
        if (s4.y >= lo && s4.y < hi) {
            const int i = s4.y - lo;
            atomicAdd(&lds[i >> 1], 1 << ((i & 1) * 16));
        }
        if (s4.z >= lo && s4.z < hi) {
            const int i = s4.z - lo;
            atomicAdd(&lds[i >> 1], 1 << ((i & 1) * 16));
        }
        if (s4.w >= lo && s4.w < hi) {
            const int i = s4.w - lo;
            atomicAdd(&lds[i >> 1], 1 << ((i & 1) * 16));
        }
    }
    __syncthreads();
    for (int i = threadIdx.x; i < nwords; i += 512) {
        const unsigned c = (unsigned)lds[i];
        const int c0 = (int)(c & 0xffffu);
        const int c1 = (int)(c >> 16);
        if (c0) atomicAdd(&dout[r * N_NODES + lo + 2 * i], c0);
        if (c1 && 2 * i + 1 < nbins)
            atomicAdd(&dout[r * N_NODES + lo + 2 * i + 1], c1);
    }
}

__global__ __launch_bounds__(256) void k_scanA(const int* __restrict__ cnt,
                                               int* __restrict__ bsum) {
    __shared__ int red[256];
    const int base = blockIdx.x * 1024 + threadIdx.x * 4;
    int s = 0;
#pragma unroll
    for (int q = 0; q < 4; ++q) {
        const int i = base + q;
        s += (i < NRN) ? cnt[i] : 0;
    }
    red[threadIdx.x] = s;
    __syncthreads();
    for (int w = 128; w > 0; w >>= 1) {
        if (threadIdx.x < w) red[threadIdx.x] += red[threadIdx.x + w];
        __syncthreads();
    }
    if (threadIdx.x == 0) bsum[blockIdx.x] = red[0];
}

__global__ __launch_bounds__(512) void k_scanB(int* __restrict__ bsum) {
    __shared__ int sc[512];
    const int t = threadIdx.x;
    sc[t] = (t < 294) ? bsum[t] : 0;
    __syncthreads();
    for (int o = 1; o < 512; o <<= 1) {
        const int v = (t >= o) ? sc[t - o] : 0;
        __syncthreads();
        sc[t] += v;
        __syncthreads();
    }
    bsum[t] = (t > 0) ? sc[t - 1] : 0;
}

__global__ __launch_bounds__(256) void k_scanC(const int* __restrict__ cnt,
                                               const int* __restrict__ bsum,
                                               int* __restrict__ G,
                                               float* __restrict__ dinv_in,
                                               int* doutc) {
    __shared__ int sc[256];
    const int t = threadIdx.x;
    const int base = blockIdx.x * 1024 + t * 4;
    int v[4];
    int ts = 0;
#pragma unroll
    for (int q = 0; q < 4; ++q) {
        const int i = base + q;
        v[q] = (i < NRN) ? cnt[i] : 0;
        ts += v[q];
    }
    sc[t] = ts;
    __syncthreads();
    for (int o = 1; o < 256; o <<= 1) {
        const int x = (t >= o) ? sc[t - o] : 0;
        __syncthreads();
        sc[t] += x;
        __syncthreads();
    }
    int run = bsum[blockIdx.x] + ((t > 0) ? sc[t - 1] : 0);
#pragma unroll
    for (int q = 0; q < 4; ++q) {
        const int i = base + q;
        if (i < NRN) {
            G[i] = run;
            dinv_in[i] = rsqrtf((float)max(v[q], 1));
            const int oc = doutc[i];
            ((float*)doutc)[i] = rsqrtf((float)max(oc, 1));
        }
        run += v[q];
    }
}

// atomic-free CSR fill, 4 edges/thread via int4.
__global__ __launch_bounds__(256) void k_fill(const int* __restrict__ es,
                                              const int* __restrict__ ed,
                                              const int* __restrict__ eslot,
                                              const int* __restrict__ G,
                                              int* __restrict__ csr) {
    const int r = blockIdx.y;
    const int e = (blockIdx.x * 256 + threadIdx.x) * 4;
    if (e + 4 > E_PER) return;
    const int gid = r * E_PER + e;
    const int4 s4 = *(const int4*)(es + gid);
    const int4 d4 = *(const int4*)(ed + gid);
    const int4 l4 = *(const int4*)(eslot + gid);
    const int rb = r * N_NODES;
    csr[G[rb + d4.x] + l4.x] = s4.x;
    csr[G[rb + d4.y] + l4.y] = s4.y;
    csr[G[rb + d4.z] + l4.z] = s4.z;
    csr[G[rb + d4.w] + l4.w] = s4.w;
}

// R21: gather1 with 8 EDGES IN FLIGHT (R7 proved 4->8-deep on the identical
// latency-bound random-row path bought ~6% on gather2_all; gather1 runs 3x
// with 256-B rows at ~3.1 TB/s beyond-L2). 16 lanes/node, direct csr reads,
// sequential per-lane add order (bit-identical to 4-deep). Tail edges read
// the zeroed pad row (index N_NODES).
__global__ __launch_bounds__(256) void k_gather1(const float* __restrict__ hp,
                                                 const int* __restrict__ csr,
                                                 const int* __restrict__ G,
                                                 const float* __restrict__ dinv,
                                                 float* __restrict__ h1,
                                                 int rbase, int first) {
    const int node = (blockIdx.x * 256 + threadIdx.x) >> 4;   // 16 lanes/node
    const int l16 = threadIdx.x & 15;
    const int idx = rbase + node;
    const int off0 = G[idx];
    const int off1 = (idx == NRN - 1) ? E_TOT : G[idx + 1];
    const int deg = off1 - off0;
    float ax = 0.f, ay = 0.f, az = 0.f, aw = 0.f;
    for (int e0 = 0; e0 < deg; e0 += 8) {
        const int sA = csr[off0 + e0];
        const int sB = (e0 + 1 < deg) ? csr[off0 + e0 + 1] : N_NODES;
        const int sC = (e0 + 2 < deg) ? csr[off0 + e0 + 2] : N_NODES;
        const int sD = (e0 + 3 < deg) ? csr[off0 + e0 + 3] : N_NODES;
        const int sE = (e0 + 4 < deg) ? csr[off0 + e0 + 4] : N_NODES;
        const int sF = (e0 + 5 < deg) ? csr[off0 + e0 + 5] : N_NODES;
        const int sG = (e0 + 6 < deg) ? csr[off0 + e0 + 6] : N_NODES;
        const int sH = (e0 + 7 < deg) ? csr[off0 + e0 + 7] : N_NODES;
        const float4 vA = *(const float4*)(hp + (size_t)sA * F_HID + l16 * 4);
        const float4 vB = *(const float4*)(hp + (size_t)sB * F_HID + l16 * 4);
        const float4 vC = *(const float4*)(hp + (size_t)sC * F_HID + l16 * 4);
        const float4 vD = *(const float4*)(hp + (size_t)sD * F_HID + l16 * 4);
        const float4 vE = *(const float4*)(hp + (size_t)sE * F_HID + l16 * 4);
        const float4 vF = *(const float4*)(hp + (size_t)sF * F_HID + l16 * 4);
        const float4 vG = *(const float4*)(hp + (size_t)sG * F_HID + l16 * 4);
        const float4 vH = *(const float4*)(hp + (size_t)sH * F_HID + l16 * 4);
        ax += vA.x; ay += vA.y; az += vA.z; aw += vA.w;
        ax += vB.x; ay += vB.y; az += vB.z; aw += vB.w;
        ax += vC.x; ay += vC.y; az += vC.z; aw += vC.w;
        ax += vD.x; ay += vD.y; az += vD.z; aw += vD.w;
        ax += vE.x; ay += vE.y; az += vE.z; aw += vE.w;
        ax += vF.x; ay += vF.y; az += vF.z; aw += vF.w;
        ax += vG.x; ay += vG.y; az += vG.z; aw += vG.w;
        ax += vH.x; ay += vH.y; az += vH.z; aw += vH.w;
    }
    const float dv = dinv[idx];
    float4* dst = (float4*)(h1 + (size_t)node * F_HID) + l16;
    float4 o;
    if (first) {
        o.x = dv * ax; o.y = dv * ay; o.z = dv * az; o.w = dv * aw;
    } else {
        const float4 pr = *dst;
        o.x = pr.x + dv * ax; o.y = pr.y + dv * ay;
        o.z = pr.z + dv * az; o.w = pr.w + dv * aw;
    }
    *dst = o;
}

// R18: 4 nodes/wave, 8 edges in flight per node. (Unchanged; proven.)
__global__ __launch_bounds__(256) void k_gather2_all(const float* __restrict__ hp0,
                                                     const float* __restrict__ hp1,
                                                     const float* __restrict__ hp2,
                                                     const int* __restrict__ csr,
                                                     const int* __restrict__ G,
                                                     const float* __restrict__ dinv,
                                                     const float* __restrict__ bmu,
                                                     const float* __restrict__ bls,
                                                     float* __restrict__ outh) {
    const int node = (blockIdx.x * 256 + threadIdx.x) >> 4;   // 16 lanes/node
    const int lane = threadIdx.x & 63;
    const int gl = lane & 15;        // group-local lane (feature id in epilogue)
    const int l8 = lane & 7;         // slice id (4 floats per slice)
    const int e2 = (lane >> 3) & 1;  // which of 2 base edges
    float ox = 0.f, oy = 0.f, oz = 0.f, ow = 0.f;
#pragma unroll
    for (int r = 0; r < NREL; ++r) {
        const float* hp = (r == 0) ? hp0 : (r == 1) ? hp1 : hp2;
        const int idx = r * N_NODES + node;
        const int off0 = G[idx];
        const int off1 = (idx == NRN - 1) ? E_TOT : G[idx + 1];
        const int deg = off1 - off0;
        float ax = 0.f, ay = 0.f, az = 0.f, aw = 0.f;
        for (int ei0 = 0; ei0 < deg; ei0 += 8) {
            const int eiA = ei0 + e2;
            const int eiB = ei0 + 2 + e2;
            const int eiC = ei0 + 4 + e2;
            const int eiD = ei0 + 6 + e2;
            const int sA = (eiA < deg) ? csr[off0 + eiA] : N_NODES;  // pad row=0
            const int sB = (eiB < deg) ? csr[off0 + eiB] : N_NODES;
            const int sC = (eiC < deg) ? csr[off0 + eiC] : N_NODES;
            const int sD = (eiD < deg) ? csr[off0 + eiD] : N_NODES;
            const float4 vA = *(const float4*)(hp + (size_t)sA * 32 + l8 * 4);
            const float4 vB = *(const float4*)(hp + (size_t)sB * 32 + l8 * 4);
            const float4 vC = *(const float4*)(hp + (size_t)sC * 32 + l8 * 4);
            const float4 vD = *(const float4*)(hp + (size_t)sD * 32 + l8 * 4);
            ax += vA.x; ay += vA.y; az += vA.z; aw += vA.w;
            ax += vB.x; ay += vB.y; az += vB.z; aw += vB.w;
            ax += vC.x; ay += vC.y; az += vC.z; aw += vC.w;
            ax += vD.x; ay += vD.y; az += vD.z; aw += vD.w;
        }
        // combine the two 8-lane edge groups within this node's 16 lanes
        ax += __shfl_xor(ax, 8);
        ay += __shfl_xor(ay, 8);
        az += __shfl_xor(az, 8);
        aw += __shfl_xor(aw, 8);
        const float dv = dinv[idx];
        ox = fmaf(dv, ax, ox);
        oy = fmaf(dv, ay, oy);
        oz = fmaf(dv, az, oz);
        ow = fmaf(dv, aw, ow);
    }
    // redistribution within each 16-lane group: lane gl owns feature gl.
    const int gb = lane & 48;                 // group base lane
    const int srcM = gb + (gl >> 2);
    const int srcL = gb + 4 + (gl >> 2);
    const float m0 = __shfl(ox, srcM), m1 = __shfl(oy, srcM),
                m2 = __shfl(oz, srcM), m3 = __shfl(ow, srcM);
    const float s0 = __shfl(ox, srcL), s1 = __shfl(oy, srcL),
                s2 = __shfl(oz, srcL), s3 = __shfl(ow, srcL);
    const float mm = (gl & 2) ? ((gl & 1) ? m3 : m2) : ((gl & 1) ? m1 : m0);
    const float ss = (gl & 2) ? ((gl & 1) ? s3 : s2) : ((gl & 1) ? s1 : s0);
    const float mean = mm + bmu[gl] + bmu[16 + gl] + bmu[32 + gl];
    const float lstd = ss + bls[gl] + bls[16 + gl] + bls[32 + gl];
    outh[(size_t)node * 16 + gl] =
        mean + jax_noise((unsigned)(node * 16 + gl)) * expf(lstd);
}

// ------------------------------------------------------ projections
// 4 output channels per thread -> 4 independent FMA chains, float4 loads.
__global__ __launch_bounds__(256) void k_project1(const float* __restrict__ x,
                                                  const float* __restrict__ W,
                                                  const float* __restrict__ dinv,
                                                  float* __restrict__ out) {
    __shared__ float ws[F_IN * F_HID];
    for (int i = threadIdx.x; i < F_IN * F_HID; i += 256) ws[i] = W[i];
    __syncthreads();
    for (int t = blockIdx.x * 256 + threadIdx.x; t < (N_NODES + 1) * 16;
         t += gridDim.x * 256) {
        const int n = t >> 4;
        const int c0 = (t & 15) << 2;
        const int nn = min(n, N_NODES - 1);
        const float4* xr = (const float4*)(x + (size_t)nn * F_IN);
        float a0 = 0.f, a1 = 0.f, a2 = 0.f, a3 = 0.f;
#pragma unroll 8
        for (int k4 = 0; k4 < F_IN / 4; ++k4) {
            const float4 xv = xr[k4];
            const float4 w0 = *(const float4*)(ws + (k4 * 4 + 0) * F_HID + c0);
            const float4 w1 = *(const float4*)(ws + (k4 * 4 + 1) * F_HID + c0);
            const float4 w2 = *(const float4*)(ws + (k4 * 4 + 2) * F_HID + c0);
            const float4 w3 = *(const float4*)(ws + (k4 * 4 + 3) * F_HID + c0);
            a0 = fmaf(xv.x, w0.x, a0); a1 = fmaf(xv.x, w0.y, a1);
            a2 = fmaf(xv.x, w0.z, a2); a3 = fmaf(xv.x, w0.w, a3);
            a0 = fmaf(xv.y, w1.x, a0); a1 = fmaf(xv.y, w1.y, a1);
            a2 = fmaf(xv.y, w1.z, a2); a3 = fmaf(xv.y, w1.w, a3);
            a0 = fmaf(xv.z, w2.x, a0); a1 = fmaf(xv.z, w2.y, a1);
            a2 = fmaf(xv.z, w2.z, a2); a3 = fmaf(xv.z, w2.w, a3);
            a0 = fmaf(xv.w, w3.x, a0); a1 = fmaf(xv.w, w3.y, a1);
            a2 = fmaf(xv.w, w3.z, a2); a3 = fmaf(xv.w, w3.w, a3);
        }
        const float dv = (n < N_NODES) ? dinv[nn] : 0.f;
        float4 o;
        o.x = a0 * dv; o.y = a1 * dv; o.z = a2 * dv; o.w = a3 * dv;
        *(float4*)(out + (size_t)n * F_HID + c0) = o;
    }
}

// R18: all 3 relations in one pass — h1 read once (was 3x), relu once,
// 3 weight sets in 24 KB LDS, writes hp20/hp21/hp22. Same k-order -> exact.
__global__ __launch_bounds__(256) void k_project2_all(const float* __restrict__ h1,
                                                      const float* __restrict__ b0,
                                                      const float* __restrict__ Wmu,
                                                      const float* __restrict__ Wls,
                                                      const float* __restrict__ dinv,
                                                      float* __restrict__ o0,
                                                      float* __restrict__ o1,
                                                      float* __restrict__ o2) {
    __shared__ float ws[NREL * F_HID * 32];
    __shared__ float bs[F_HID];
    for (int i = threadIdx.x; i < NREL * F_HID * 32; i += 256) {
        const int r = i >> 11;          // /2048
        const int j = i & 2047;
        const int k = j >> 5, c = j & 31;
        ws[i] = (c < 16) ? Wmu[r * F_HID * 16 + k * 16 + c]
                         : Wls[r * F_HID * 16 + k * 16 + (c - 16)];
    }
    if (threadIdx.x < F_HID)
        bs[threadIdx.x] = b0[threadIdx.x] + b0[64 + threadIdx.x] + b0[128 + threadIdx.x];
    __syncthreads();
    for (int t = blockIdx.x * 256 + threadIdx.x; t < (N_NODES + 1) * 8;
         t += gridDim.x * 256) {
        const int n = t >> 3;
        const int c0 = (t & 7) << 2;
        const int nn = min(n, N_NODES - 1);
        const float4* hr = (const float4*)(h1 + (size_t)nn * F_HID);
        float a00 = 0.f, a01 = 0.f, a02 = 0.f, a03 = 0.f;
        float a10 = 0.f, a11 = 0.f, a12 = 0.f, a13 = 0.f;
        float a20 = 0.f, a21 = 0.f, a22 = 0.f, a23 = 0.f;
#pragma unroll 2
        for (int k4 = 0; k4 < F_HID / 4; ++k4) {
            const float4 hv = hr[k4];
            const float4 bv = *(const float4*)(bs + k4 * 4);
            const float r0 = fmaxf(hv.x + bv.x, 0.f);
            const float r1 = fmaxf(hv.y + bv.y, 0.f);
            const float r2 = fmaxf(hv.z + bv.z, 0.f);
            const float r3 = fmaxf(hv.w + bv.w, 0.f);
#pragma unroll
            for (int rr = 0; rr < NREL; ++rr) {
                const float* wb = ws + rr * F_HID * 32;
                const float4 w0 = *(const float4*)(wb + (k4 * 4 + 0) * 32 + c0);
                const float4 w1 = *(const float4*)(wb + (k4 * 4 + 1) * 32 + c0);
                const float4 w2 = *(const float4*)(wb + (k4 * 4 + 2) * 32 + c0);
                const float4 w3 = *(const float4*)(wb + (k4 * 4 + 3) * 32 + c0);
                float* pa0 = (rr == 0) ? &a00 : (rr == 1) ? &a10 : &a20;
                float* pa1 = (rr == 0) ? &a01 : (rr == 1) ? &a11 : &a21;
                float* pa2 = (rr == 0) ? &a02 : (rr == 1) ? &a12 : &a22;
                float* pa3 = (rr == 0) ? &a03 : (rr == 1) ? &a13 : &a23;
                *pa0 = fmaf(r0, w0.x, *pa0); *pa1 = fmaf(r0, w0.y, *pa1);
                *pa2 = fmaf(r0, w0.z, *pa2); *pa3 = fmaf(r0, w0.w, *pa3);
                *pa0 = fmaf(r1, w1.x, *pa0); *pa1 = fmaf(r1, w1.y, *pa1);
                *pa2 = fmaf(r1, w1.z, *pa2); *pa3 = fmaf(r1, w1.w, *pa3);
                *pa0 = fmaf(r2, w2.x, *pa0); *pa1 = fmaf(r2, w2.y, *pa1);
                *pa2 = fmaf(r2, w2.z, *pa2); *pa3 = fmaf(r2, w2.w, *pa3);
                *pa0 = fmaf(r3, w3.x, *pa0); *pa1 = fmaf(r3, w3.y, *pa1);
                *pa2 = fmaf(r3, w3.z, *pa2); *pa3 = fmaf(r3, w3.w, *pa3);
            }
        }
        const bool valid = (n < N_NODES);
        const float dv0 = valid ? dinv[nn] : 0.f;
        const float dv1 = valid ? dinv[N_NODES + nn] : 0.f;
        const float dv2 = valid ? dinv[2 * N_NODES + nn] : 0.f;
        float4 q;
        q.x = a00 * dv0; q.y = a01 * dv0; q.z = a02 * dv0; q.w = a03 * dv0;
        *(float4*)(o0 + (size_t)n * 32 + c0) = q;
        q.x = a10 * dv1; q.y = a11 * dv1; q.z = a12 * dv1; q.w = a13 * dv1;
        *(float4*)(o1 + (size_t)n * 32 + c0) = q;
        q.x = a20 * dv2; q.y = a21 * dv2; q.z = a22 * dv2; q.w = a23 * dv2;
        *(float4*)(o2 + (size_t)n * 32 + c0) = q;
    }
}

// kept for the fallback path
__global__ __launch_bounds__(256) void k_project2(const float* __restrict__ h1,
                                                  const float* __restrict__ b0,
                                                  const float* __restrict__ Wmu,
                                                  const float* __restrict__ Wls,
                                                  const float* __restrict__ dinv,
                                                  float* __restrict__ out) {
    __shared__ float ws[F_HID * 32];
    __shared__ float bs[F_HID];
    for (int i = threadIdx.x; i < F_HID * 32; i += 256) {
        const int k = i >> 5, c = i & 31;
        ws[i] = (c < 16) ? Wmu[k * 16 + c] : Wls[k * 16 + (c - 16)];
    }
    if (threadIdx.x < F_HID)
        bs[threadIdx.x] = b0[threadIdx.x] + b0[64 + threadIdx.x] + b0[128 + threadIdx.x];
    __syncthreads();
    for (int t = blockIdx.x * 256 + threadIdx.x; t < (N_NODES + 1) * 8;
         t += gridDim.x * 256) {
        const int n = t >> 3;
        const int c0 = (t & 7) << 2;
        const int nn = min(n, N_NODES - 1);
        const float4* hr = (const float4*)(h1 + (size_t)nn * F_HID);
        float a0 = 0.f, a1 = 0.f, a2 = 0.f, a3 = 0.f;
#pragma unroll 4
        for (int k4 = 0; k4 < F_HID / 4; ++k4) {
            const float4 hv = hr[k4];
            const float4 bv = *(const float4*)(bs + k4 * 4);
            const float r0 = fmaxf(hv.x + bv.x, 0.f);
            const float r1 = fmaxf(hv.y + bv.y, 0.f);
            const float r2 = fmaxf(hv.z + bv.z, 0.f);
            const float r3 = fmaxf(hv.w + bv.w, 0.f);
            const float4 w0 = *(const float4*)(ws + (k4 * 4 + 0) * 32 + c0);
            const float4 w1 = *(const float4*)(ws + (k4 * 4 + 1) * 32 + c0);
            const float4 w2 = *(const float4*)(ws + (k4 * 4 + 2) * 32 + c0);
            const float4 w3 = *(const float4*)(ws + (k4 * 4 + 3) * 32 + c0);
            a0 = fmaf(r0, w0.x, a0); a1 = fmaf(r0, w0.y, a1);
            a2 = fmaf(r0, w0.z, a2); a3 = fmaf(r0, w0.w, a3);
            a0 = fmaf(r1, w1.x, a0); a1 = fmaf(r1, w1.y, a1);
            a2 = fmaf(r1, w1.z, a2); a3 = fmaf(r1, w1.w, a3);
            a0 = fmaf(r2, w2.x, a0); a1 = fmaf(r2, w2.y, a1);
            a2 = fmaf(r2, w2.z, a2); a3 = fmaf(r2, w2.w, a3);
            a0 = fmaf(r3, w3.x, a0); a1 = fmaf(r3, w3.y, a1);
            a2 = fmaf(r3, w3.z, a2); a3 = fmaf(r3, w3.w, a3);
        }
        const float dv = (n < N_NODES) ? dinv[nn] : 0.f;
        float4 o;
        o.x = a0 * dv; o.y = a1 * dv; o.z = a2 * dv; o.w = a3 * dv;
        *(float4*)(out + (size_t)n * 32 + c0) = o;
    }
}

__global__ __launch_bounds__(256) void k_scores(const int* __restrict__ ps,
                                                const int* __restrict__ pd,
                                                const int* __restrict__ ns,
                                                const int* __restrict__ nd,
                                                const float* __restrict__ h,
                                                float* __restrict__ out) {
    const int i = blockIdx.x * 256 + threadIdx.x;
    if (i >= 2 * EP) return;
    const int j = (i < EP) ? i : i - EP;
    const int a = (i < EP) ? ps[j] : ns[j];
    const int b = (i < EP) ? pd[j] : nd[j];
    const float4* ha = (const float4*)(h + (size_t)a * 16);
    const float4* hb = (const float4*)(h + (size_t)b * 16);
    float s = 0.f;
#pragma unroll
    for (int q = 0; q < 4; ++q) {
        const float4 u = ha[q];
        const float4 v = hb[q];
        s += u.x * v.x + u.y * v.y + u.z * v.z + u.w * v.w;
    }
    out[i] = s;
}

// --------------------------------------------- fallback (R7 atomic-scatter)
__global__ __launch_bounds__(256) void k_degrees(const int* __restrict__ es,
                                                 const int* __restrict__ ed,
                                                 float* __restrict__ dout,
                                                 float* __restrict__ din) {
    const int r = blockIdx.y;
    const int e = blockIdx.x * 256 + threadIdx.x;
    const int s = es[r * E_PER + e];
    const int d = ed[r * E_PER + e];
    atomAddF(&dout[r * N_NODES + s], 1.0f);
    atomAddF(&din[r * N_NODES + d], 1.0f);
}

__global__ __launch_bounds__(256) void k_finalize_deg(float* __restrict__ d) {
    const int i = blockIdx.x * 256 + threadIdx.x;
    if (i < 2 * NRN) d[i] = 1.0f / sqrtf(fmaxf(d[i], 1.0f));
}

__global__ __launch_bounds__(256) void k_scatter1(const float* __restrict__ hp,
                                                  const int* __restrict__ es,
                                                  const int* __restrict__ ed,
                                                  const float* __restrict__ din,
                                                  float* __restrict__ acc) {
    const int t = blockIdx.x * 256 + threadIdx.x;
    const int e = t >> 6;
    const int lane = t & 63;
    const int s = es[e];
    const int d = ed[e];
    const float v = hp[s * F_HID + lane] * din[d];
    atomAddF(&acc[d * F_HID + lane], v);
}

__global__ __launch_bounds__(256) void k_scatter2(const float* __restrict__ hp,
                                                  const int* __restrict__ es,
                                                  const int* __restrict__ ed,
                                                  const float* __restrict__ din,
                                                  float* __restrict__ acc) {
    const int t = blockIdx.x * 256 + threadIdx.x;
    const int e = t >> 5;
    const int c = t & 31;
    const int s = es[e];
    const int d = ed[e];
    const float v = hp[s * 32 + c] * din[d];
    atomAddF(&acc[d * 32 + c], v);
}

__global__ __launch_bounds__(256) void k_finalize(const float* __restrict__ l2,
                                                  const float* __restrict__ bmu,
                                                  const float* __restrict__ bls,
                                                  float* __restrict__ outh) {
    const int i = blockIdx.x * 256 + threadIdx.x;
    const int n = i >> 4, c = i & 15;
    const float mean = l2[n * 32 + c] + bmu[c] + bmu[16 + c] + bmu[32 + c];
    const float lstd = l2[n * 32 + 16 + c] + bls[c] + bls[16 + c] + bls[32 + c];
    const float z = jax_noise((unsigned)i);
    outh[i] = mean + z * expf(lstd);
}

extern "C" void kernel_launch(void* const* d_in, const int* in_sizes, int n_in,
                              void* d_out, int out_size, void* d_ws, size_t ws_size,
                              hipStream_t stream) {
    const float* x   = (const float*)d_in[0];
    const float* W0  = (const float*)d_in[1];
    const float* b0  = (const float*)d_in[2];
    const float* Wmu = (const float*)d_in[3];
    const float* bmu = (const float*)d_in[4];
    const float* Wls = (const float*)d_in[5];
    const float* bls = (const float*)d_in[6];
    const int* es = (const int*)d_in[7];
    const int* ed = (const int*)d_in[8];
    const int* ps = (const int*)d_in[9];
    const int* pd = (const int*)d_in[10];
    const int* ns = (const int*)d_in[11];
    const int* nd = (const int*)d_in[12];
    float* out = (float*)d_out;
    float* wsf = (float*)d_ws;

    if (ws_size >= (size_t)WS_NEED_CSR * sizeof(float)) {
        // ---------------- CSR path ----------------
        int*   doutc   = (int*)(wsf + OFF_DOUT);    // int counts -> float rsqrt
        float* doutf   = wsf + OFF_DOUT;            // float view after scanC
        float* dinv_in = wsf + OFF_DINVIN;
        int*   cnt     = (int*)(wsf + OFF_CNT);
        int*   G       = (int*)(wsf + OFF_G);
        int*   bsum    = (int*)(wsf + OFF_BSUM);
        int*   csr     = (int*)(wsf + OFF_CSR);
        int*   eslot   = (int*)(wsf + OFF_ESLOT);   // aliases hproj region
        float* hproj   = wsf + OFF_HPROJ;           // (N+1) x 64, layer 1
        float* hp20    = wsf + OFF_HPROJ;           // (N+1) x 32, layer 2 r0
        float* hp21    = wsf + OFF_HPROJ + HP2SZ;   // (N+1) x 32, layer 2 r1
        float* hp22    = wsf + OFF_HP22;            // (N+1) x 32, layer 2 r2
        float* h1acc   = wsf + OFF_H1;

        hipMemsetAsync(doutc, 0, (size_t)NRN * sizeof(int), stream);
        hipMemsetAsync(cnt, 0, (size_t)NRN * sizeof(int), stream);

        k_histin<<<dim3(NBLK, NSEG, NREL), 512, SEGSZ * sizeof(int), stream>>>(
            ed, cnt, eslot);
        k_histout<<<dim3(NBLK, NSEGO, NREL), 512, (SEGO / 2) * sizeof(int), stream>>>(
            es, doutc);
        k_scanA<<<294, 256, 0, stream>>>(cnt, bsum);
        k_scanB<<<1, 512, 0, stream>>>(bsum);
        k_scanC<<<294, 256, 0, stream>>>(cnt, bsum, G, dinv_in, doutc);
        k_fill<<<dim3((E_PER / 4 + 255) / 256, NREL), 256, 0, stream>>>(
            es, ed, eslot, G, csr);

        for (int r = 0; r < NREL; ++r) {
            k_project1<<<1280, 256, 0, stream>>>(
                x, W0 + (size_t)r * F_IN * F_HID, doutf + (size_t)r * N_NODES, hproj);
            k_gather1<<<N_NODES / 16, 256, 0, stream>>>(
                hproj, csr, G, dinv_in, h1acc, r * N_NODES, r == 0);
        }
        k_project2_all<<<1024, 256, 0, stream>>>(
            h1acc, b0, Wmu, Wls, doutf, hp20, hp21, hp22);
        k_gather2_all<<<N_NODES / 16, 256, 0, stream>>>(
            hp20, hp21, hp22, csr, G, dinv_in, bmu, bls, out + 2 * EP);
        k_scores<<<(2 * EP + 255) / 256, 256, 0, stream>>>(
            ps, pd, ns, nd, out + 2 * EP, out);
    } else {
        // ---------------- fallback: proven R7 atomic path ----------------
        float* dinv_out = wsf + ODINV_OUT;
        float* dinv_in  = wsf + ODINV_IN;
        float* h1acc    = wsf + OH1ACC;
        float* hproj    = wsf + OHPROJ;
        float* l2acc    = wsf + OL2ACC;

        hipMemsetAsync(dinv_out, 0, (size_t)2 * NRN * sizeof(float), stream);
        hipMemsetAsync(h1acc, 0, (size_t)N_NODES * F_HID * sizeof(float), stream);
        hipMemsetAsync(l2acc, 0, (size_t)N_NODES * 32 * sizeof(float), stream);

        k_degrees<<<dim3(E_PER / 256, NREL), 256, 0, stream>>>(es, ed, dinv_out, dinv_in);
        k_finalize_deg<<<(2 * NRN + 255) / 256, 256, 0, stream>>>(wsf);

        for (int r = 0; r < NREL; ++r) {
            k_project1<<<1280, 256, 0, stream>>>(
                x, W0 + (size_t)r * F_IN * F_HID, dinv_out + (size_t)r * N_NODES, hproj);
            k_scatter1<<<E_PER / 4, 256, 0, stream>>>(
                hproj, es + (size_t)r * E_PER, ed + (size_t)r * E_PER,
                dinv_in + (size_t)r * N_NODES, h1acc);
        }
        for (int r = 0; r < NREL; ++r) {
            k_project2<<<1024, 256, 0, stream>>>(
                h1acc, b0, Wmu + (size_t)r * F_HID * F_OUT,
                Wls + (size_t)r * F_HID * F_OUT, dinv_out + (size_t)r * N_NODES, hproj);
            k_scatter2<<<E_PER / 8, 256, 0, stream>>>(
                hproj, es + (size_t)r * E_PER, ed + (size_t)r * E_PER,
                dinv_in + (size_t)r * N_NODES, l2acc);
        }
        k_finalize<<<N_NODES * F_OUT / 256, 256, 0, stream>>>(
            l2acc, bmu, bls, out + 2 * EP);
        k_scores<<<(2 * EP + 255) / 256, 256, 0, stream>>>(
            ps, pd, ns, nd, out + 2 * EP, out);
    }
}